// Round 1
// baseline (1099.836 us; speedup 1.0000x reference)
//
#include <hip/hip_runtime.h>
#include <stdint.h>
#include <math.h>

// ---- configuration -------------------------------------------------------
// JAX >= 0.5 defaults jax_threefry_partitionable=True. If bench absmax comes
// back O(1) with everything else sane, flip this to 0 (legacy bit scheme).
#define MASK_VARIANT_PARTITIONABLE 1

static constexpr int NN  = 1024;   // N
static constexpr int DIN = 512;    // D_IN
static constexpr int DD  = 128;    // D_OUT

// ---- threefry2x32, key = jax.random.key(42) => (k1,k2) = (0,42) ----------
__device__ __forceinline__ uint32_t rotl32(uint32_t x, uint32_t r) {
  return (x << r) | (x >> (32u - r));
}

__device__ __forceinline__ void threefry2x32(uint32_t x0, uint32_t x1,
                                             uint32_t& o0, uint32_t& o1) {
  const uint32_t k0 = 0u;
  const uint32_t k1 = 42u;
  const uint32_t k2 = k0 ^ k1 ^ 0x1BD11BDAu;
  x0 += k0; x1 += k1;
#define TF_ROUND(r) { x0 += x1; x1 = rotl32(x1, r); x1 ^= x0; }
  TF_ROUND(13u) TF_ROUND(15u) TF_ROUND(26u) TF_ROUND(6u)
  x0 += k1; x1 += k2 + 1u;
  TF_ROUND(17u) TF_ROUND(29u) TF_ROUND(16u) TF_ROUND(24u)
  x0 += k2; x1 += k0 + 2u;
  TF_ROUND(13u) TF_ROUND(15u) TF_ROUND(26u) TF_ROUND(6u)
  x0 += k0; x1 += k1 + 3u;
  TF_ROUND(17u) TF_ROUND(29u) TF_ROUND(16u) TF_ROUND(24u)
  x0 += k1; x1 += k2 + 4u;
  TF_ROUND(13u) TF_ROUND(15u) TF_ROUND(26u) TF_ROUND(6u)
  x0 += k2; x1 += k0 + 5u;
#undef TF_ROUND
  o0 = x0; o1 = x1;
}

// keep-probability 0.6; idx is the C-order linear index into (N, D, N).
__device__ __forceinline__ bool keep_mask(uint32_t idx) {
  uint32_t o0, o1, bits;
#if MASK_VARIANT_PARTITIONABLE
  // partitionable: counts64 = idx (hi word 0), bits = out0 ^ out1
  threefry2x32(0u, idx, o0, o1);
  bits = o0 ^ o1;
#else
  // original: iota split in halves -> pair (j, j+half); word0 for first half
  const uint32_t half = (uint32_t)(NN) * (uint32_t)(DD) * (uint32_t)(NN) / 2u;
  const uint32_t j = (idx < half) ? idx : (idx - half);
  threefry2x32(j, j + half, o0, o1);
  bits = (idx < half) ? o0 : o1;
#endif
  const float u = __uint_as_float((bits >> 9) | 0x3f800000u) - 1.0f;
  return u < 0.6f;
}

// ---- K1: q,k,v,scale = x_i @ W.T + b  (grid: 1024 x 4, block: 128) -------
__global__ void lin_kernel(const float* __restrict__ x1, const float* __restrict__ x2,
                           const float* __restrict__ x3, const float* __restrict__ x4,
                           const float* __restrict__ W, const float* __restrict__ bias,
                           float* __restrict__ q, float* __restrict__ kk,
                           float* __restrict__ v, float* __restrict__ sc) {
  __shared__ float xs[DIN];
  const int n   = blockIdx.x;
  const int mat = blockIdx.y;
  const int d   = threadIdx.x;
  const float* x = (mat == 0) ? x1 : (mat == 1) ? x2 : (mat == 2) ? x3 : x4;
  for (int c = d; c < DIN; c += DD) xs[c] = x[n * DIN + c];
  __syncthreads();
  const float* Wr = W + d * DIN;
  float acc = 0.f;
#pragma unroll 4
  for (int c = 0; c < DIN; ++c) acc = fmaf(xs[c], Wr[c], acc);
  acc += bias[d];
  float* o = (mat == 0) ? q : (mat == 1) ? kk : (mat == 2) ? v : sc;
  o[n * DD + d] = acc;
}

// ---- K2: inv_scale = softmax(scale, axis=0)  (grid: 128, block: 256) -----
__global__ void colsoftmax_kernel(const float* __restrict__ sc,
                                  float* __restrict__ inv) {
  __shared__ float red[256];
  const int d = blockIdx.x;
  const int t = threadIdx.x;
  float vals[4];
  float mx = -INFINITY;
#pragma unroll
  for (int i = 0; i < 4; ++i) {
    vals[i] = sc[(size_t)(t + 256 * i) * DD + d];
    mx = fmaxf(mx, vals[i]);
  }
  red[t] = mx; __syncthreads();
  for (int s = 128; s > 0; s >>= 1) {
    if (t < s) red[t] = fmaxf(red[t], red[t + s]);
    __syncthreads();
  }
  mx = red[0]; __syncthreads();
  float e[4]; float sm = 0.f;
#pragma unroll
  for (int i = 0; i < 4; ++i) { e[i] = expf(vals[i] - mx); sm += e[i]; }
  red[t] = sm; __syncthreads();
  for (int s = 128; s > 0; s >>= 1) {
    if (t < s) red[t] += red[t + s];
    __syncthreads();
  }
  sm = red[0];
#pragma unroll
  for (int i = 0; i < 4; ++i)
    inv[(size_t)(t + 256 * i) * DD + d] = e[i] / sm;
}

// ---- K3: qk = q @ k.T  (grid: 64 x 64, block: 16 x 16) -------------------
__global__ void qk_kernel(const float* __restrict__ q, const float* __restrict__ k,
                          float* __restrict__ qkout) {
  __shared__ float qs[16][DD + 1];
  __shared__ float ks[16][DD + 1];
  const int tx = threadIdx.x, ty = threadIdx.y;
  const int tm = blockIdx.x * 16, tn = blockIdx.y * 16;
  const int t = ty * 16 + tx;
  for (int i = t; i < 16 * DD; i += 256) {
    const int r = i >> 7, c = i & 127;
    qs[r][c] = q[(size_t)(tn + r) * DD + c];
    ks[r][c] = k[(size_t)(tm + r) * DD + c];
  }
  __syncthreads();
  float acc = 0.f;
#pragma unroll 4
  for (int c = 0; c < DD; ++c) acc = fmaf(qs[ty][c], ks[tx][c], acc);
  qkout[(size_t)(tn + ty) * NN + tm + tx] = acc;
}

// ---- K4: fused scale-softmax + dropout + (P @ V)  (grid: 1024, block:256)-
__global__ __launch_bounds__(256) void attn_kernel(
    const float* __restrict__ qk, const float* __restrict__ inv_scale,
    const float* __restrict__ v, float* __restrict__ out) {
  __shared__ float qkrow[NN];     // 4 KB
  __shared__ float invrow[DD];
  __shared__ float rmax[DD];
  __shared__ float rs[DD];        // 1 / (rowsum * 0.6)
  __shared__ float red[256];
  __shared__ float Pt[64][DD];    // 32 KB, [m_local][d]
  __shared__ float Vt[64][DD];    // 32 KB, [m_local][k]

  const int n = blockIdx.x;
  const int t = threadIdx.x;

  for (int i = t; i < NN; i += 256) qkrow[i] = qk[(size_t)n * NN + i];
  if (t < DD) invrow[t] = inv_scale[n * DD + t];
  __syncthreads();

  // block-wide max of qk row (monotone div => rowmax[d] = qkmax / inv[d])
  float mx = -INFINITY;
  for (int i = t; i < NN; i += 256) mx = fmaxf(mx, qkrow[i]);
  red[t] = mx; __syncthreads();
  for (int s = 128; s > 0; s >>= 1) {
    if (t < s) red[t] = fmaxf(red[t], red[t + s]);
    __syncthreads();
  }
  const float qkmax = red[0];
  __syncthreads();

  // per-d row sums: 2 threads per d, 512 m each
  {
    const int d = t >> 1;
    const int h = t & 1;
    const float invd = invrow[d];
    const float rm = qkmax / invd;
    float s = 0.f;
    for (int m = h * 512; m < h * 512 + 512; ++m)
      s += expf(qkrow[m] / invd - rm);
    red[t] = s;
    __syncthreads();
    if (h == 0) {
      rmax[d] = rm;
      rs[d] = 1.0f / ((red[2 * d] + red[2 * d + 1]) * 0.6f);
    }
  }
  __syncthreads();

  // accumulators: thread owns d0..d0+3 (rows) x k0..k0+15 (cols)
  float acc[4][16];
#pragma unroll
  for (int a = 0; a < 4; ++a)
#pragma unroll
    for (int b = 0; b < 16; ++b) acc[a][b] = 0.f;

  const int kg = t >> 5;       // 0..7
  const int dg = t & 31;       // 0..31
  const int d0 = dg * 4;
  const int k0 = kg * 16;

  for (int tile = 0; tile < 16; ++tile) {
    const int m0 = tile * 64;
    __syncthreads();  // previous-tile reads of Pt/Vt are done
    // stage V tile (coalesced)
    for (int i = t; i < 64 * DD; i += 256) {
      const int ml = i >> 7;
      const int kkk = i & 127;
      Vt[ml][kkk] = v[(size_t)(m0 + ml) * DD + kkk];
    }
    // compute P tile with dropout
    for (int i = t; i < 64 * DD; i += 256) {
      const int ml = i >> 7;
      const int d2 = i & 127;
      const int m = m0 + ml;
      const float logit = qkrow[m] / invrow[d2];
      const float e = expf(logit - rmax[d2]);
      const uint32_t idx = (uint32_t)(n * DD + d2) * 1024u + (uint32_t)m;
      Pt[ml][d2] = keep_mask(idx) ? e * rs[d2] : 0.f;
    }
    __syncthreads();
    // out[d,k] += P[d,m] * V[m,k] over this m-tile
#pragma unroll 2
    for (int ml = 0; ml < 64; ++ml) {
      const float4 p4 = *(const float4*)&Pt[ml][d0];
      const float4 va = *(const float4*)&Vt[ml][k0 + 0];
      const float4 vb = *(const float4*)&Vt[ml][k0 + 4];
      const float4 vc = *(const float4*)&Vt[ml][k0 + 8];
      const float4 vd = *(const float4*)&Vt[ml][k0 + 12];
      const float pv[4] = {p4.x, p4.y, p4.z, p4.w};
      const float vv[16] = {va.x, va.y, va.z, va.w, vb.x, vb.y, vb.z, vb.w,
                            vc.x, vc.y, vc.z, vc.w, vd.x, vd.y, vd.z, vd.w};
#pragma unroll
      for (int a = 0; a < 4; ++a)
#pragma unroll
        for (int b = 0; b < 16; ++b)
          acc[a][b] = fmaf(pv[a], vv[b], acc[a][b]);
    }
  }

  // write out [n][d0..d0+3][k0..k0+15]
#pragma unroll
  for (int a = 0; a < 4; ++a) {
    float* op = out + ((size_t)(n * DD + d0 + a)) * DD + k0;
#pragma unroll
    for (int b = 0; b < 16; b += 4) {
      *(float4*)(op + b) =
          make_float4(acc[a][b], acc[a][b + 1], acc[a][b + 2], acc[a][b + 3]);
    }
  }
}

// ---- launch --------------------------------------------------------------
extern "C" void kernel_launch(void* const* d_in, const int* in_sizes, int n_in,
                              void* d_out, int out_size, void* d_ws, size_t ws_size,
                              hipStream_t stream) {
  const float* x1 = (const float*)d_in[0];
  const float* x2 = (const float*)d_in[1];
  const float* x3 = (const float*)d_in[2];
  const float* x4 = (const float*)d_in[3];
  const float* W  = (const float*)d_in[4];
  const float* b  = (const float*)d_in[5];
  float* out = (float*)d_out;

  float* ws   = (float*)d_ws;
  float* q    = ws;                 // 1024*128
  float* k    = ws + 131072;        // 1024*128
  float* v    = ws + 262144;        // 1024*128
  float* sc   = ws + 393216;        // 1024*128
  float* inv  = ws + 524288;        // 1024*128
  float* qkm  = ws + 655360;        // 1024*1024
  // total ws use: (655360 + 1048576) * 4 B = ~6.8 MB

  lin_kernel<<<dim3(NN, 4), 128, 0, stream>>>(x1, x2, x3, x4, W, b, q, k, v, sc);
  colsoftmax_kernel<<<DD, 256, 0, stream>>>(sc, inv);
  qk_kernel<<<dim3(64, 64), dim3(16, 16), 0, stream>>>(q, k, qkm);
  attn_kernel<<<NN, 256, 0, stream>>>(qkm, inv, v, out);
}

// Round 2
// 209.042 us; speedup vs baseline: 5.2613x; 5.2613x over previous
//
#include <hip/hip_runtime.h>
#include <stdint.h>
#include <math.h>

static constexpr int NN  = 1024;   // N
static constexpr int DIN = 512;    // D_IN
static constexpr int DD  = 128;    // D_OUT

typedef __attribute__((ext_vector_type(8))) short short8v;
typedef __attribute__((ext_vector_type(4))) short short4v;
typedef __attribute__((ext_vector_type(4))) float float4v;

// ---- threefry2x32, key = jax.random.key(42) => (0,42), partitionable ----
__device__ __forceinline__ uint32_t rotl32(uint32_t x, uint32_t r) {
  return (x << r) | (x >> (32u - r));
}

__device__ __forceinline__ bool keep_mask(uint32_t idx) {
  uint32_t x0 = 0u, x1 = idx;
  const uint32_t k0 = 0u, k1 = 42u;
  const uint32_t k2 = k0 ^ k1 ^ 0x1BD11BDAu;
  x0 += k0; x1 += k1;
#define TF_ROUND(r) { x0 += x1; x1 = rotl32(x1, r); x1 ^= x0; }
  TF_ROUND(13u) TF_ROUND(15u) TF_ROUND(26u) TF_ROUND(6u)
  x0 += k1; x1 += k2 + 1u;
  TF_ROUND(17u) TF_ROUND(29u) TF_ROUND(16u) TF_ROUND(24u)
  x0 += k2; x1 += k0 + 2u;
  TF_ROUND(13u) TF_ROUND(15u) TF_ROUND(26u) TF_ROUND(6u)
  x0 += k0; x1 += k1 + 3u;
  TF_ROUND(17u) TF_ROUND(29u) TF_ROUND(16u) TF_ROUND(24u)
  x0 += k1; x1 += k2 + 4u;
  TF_ROUND(13u) TF_ROUND(15u) TF_ROUND(26u) TF_ROUND(6u)
  x0 += k2; x1 += k0 + 5u;
#undef TF_ROUND
  const uint32_t bits = x0 ^ x1;
  const float u = __uint_as_float((bits >> 9) | 0x3f800000u) - 1.0f;
  return u < 0.6f;
}

__device__ __forceinline__ ushort f2bf(float f) {  // RNE float->bf16
  uint32_t u = __float_as_uint(f);
  u += 0x7fffu + ((u >> 16) & 1u);
  return (ushort)(u >> 16);
}

// ---- K1: q,k,v,scale = x_i @ W.T + b --------------------------------------
// grid (64, 4), block 256. Block = 16 n-rows x 128 d for one input matrix.
// Ws stride 66 dwords: read bank = 2*tx -> 2-way within 16 lanes (free, m136).
__global__ __launch_bounds__(256) void lin_kernel(
    const float* __restrict__ x1, const float* __restrict__ x2,
    const float* __restrict__ x3, const float* __restrict__ x4,
    const float* __restrict__ W, const float* __restrict__ bias,
    float* __restrict__ q, float* __restrict__ kk,
    float* __restrict__ v, float* __restrict__ sc) {
  __shared__ float Ws[128 * 66];
  __shared__ float Xs[16 * 68];
  const int t = threadIdx.x;
  const int n0 = blockIdx.x * 16;
  const int mat = blockIdx.y;
  const float* x = (mat == 0) ? x1 : (mat == 1) ? x2 : (mat == 2) ? x3 : x4;
  float* o = (mat == 0) ? q : (mat == 1) ? kk : (mat == 2) ? v : sc;
  const int tx = t & 31;   // d-lane: owns d = tx + 32j
  const int ty = t >> 5;   // n-pair: n = n0 + ty*2 + r
  float acc[2][4] = {{0.f, 0.f, 0.f, 0.f}, {0.f, 0.f, 0.f, 0.f}};
  for (int kt = 0; kt < 8; ++kt) {
    const int k0 = kt * 64;
    __syncthreads();
    // stage W tile 128x64 (float2 writes: stride 66 is 8B-aligned rows)
    for (int it = 0; it < 8; ++it) {
      const int i = t + 256 * it;
      const int r = i >> 4, c = (i & 15) * 4;
      const float4 wv = *(const float4*)&W[r * DIN + k0 + c];
      *(float2*)&Ws[r * 66 + c]     = make_float2(wv.x, wv.y);
      *(float2*)&Ws[r * 66 + c + 2] = make_float2(wv.z, wv.w);
    }
    // stage X tile 16x64
    {
      const int r = t >> 4, c = (t & 15) * 4;
      *(float4*)&Xs[r * 68 + c] = *(const float4*)&x[(n0 + r) * DIN + k0 + c];
    }
    __syncthreads();
    for (int c4 = 0; c4 < 64; c4 += 4) {
      const float4 xa = *(const float4*)&Xs[(ty * 2 + 0) * 68 + c4];
      const float4 xb = *(const float4*)&Xs[(ty * 2 + 1) * 68 + c4];
#pragma unroll
      for (int j = 0; j < 4; ++j) {
        const float2 w0 = *(const float2*)&Ws[(tx + 32 * j) * 66 + c4];
        const float2 w1 = *(const float2*)&Ws[(tx + 32 * j) * 66 + c4 + 2];
        acc[0][j] = fmaf(xa.x, w0.x, fmaf(xa.y, w0.y, fmaf(xa.z, w1.x, fmaf(xa.w, w1.y, acc[0][j]))));
        acc[1][j] = fmaf(xb.x, w0.x, fmaf(xb.y, w0.y, fmaf(xb.z, w1.x, fmaf(xb.w, w1.y, acc[1][j]))));
      }
    }
  }
#pragma unroll
  for (int r = 0; r < 2; ++r)
#pragma unroll
    for (int j = 0; j < 4; ++j) {
      const int d = tx + 32 * j;
      o[(n0 + ty * 2 + r) * DD + d] = acc[r][j] + bias[d];
    }
}

// ---- K2: inv_scale = softmax(scale, axis=0)  (grid 128, block 256) -------
__global__ void colsoftmax_kernel(const float* __restrict__ sc,
                                  float* __restrict__ inv) {
  __shared__ float red[256];
  const int d = blockIdx.x;
  const int t = threadIdx.x;
  float vals[4];
  float mx = -INFINITY;
#pragma unroll
  for (int i = 0; i < 4; ++i) {
    vals[i] = sc[(size_t)(t + 256 * i) * DD + d];
    mx = fmaxf(mx, vals[i]);
  }
  red[t] = mx; __syncthreads();
  for (int s = 128; s > 0; s >>= 1) {
    if (t < s) red[t] = fmaxf(red[t], red[t + s]);
    __syncthreads();
  }
  mx = red[0]; __syncthreads();
  float e[4]; float sm = 0.f;
#pragma unroll
  for (int i = 0; i < 4; ++i) { e[i] = expf(vals[i] - mx); sm += e[i]; }
  red[t] = sm; __syncthreads();
  for (int s = 128; s > 0; s >>= 1) {
    if (t < s) red[t] += red[t + s];
    __syncthreads();
  }
  sm = red[0];
#pragma unroll
  for (int i = 0; i < 4; ++i)
    inv[(size_t)(t + 256 * i) * DD + d] = e[i] / sm;
}

// ---- K3: qk = q @ k.T  (grid 16x16, block 256; 64x64 tile, 4x4/thread) ---
__global__ __launch_bounds__(256) void qk_kernel(
    const float* __restrict__ q, const float* __restrict__ kref,
    float* __restrict__ qkout) {
  __shared__ float qs[64 * 132];
  __shared__ float ks[64 * 132];
  const int t = threadIdx.x;
  const int tx = t & 15, ty = t >> 4;
  const int tm = blockIdx.x * 64, tn = blockIdx.y * 64;
  for (int it = 0; it < 8; ++it) {
    const int i = t + 256 * it;
    const int r = i >> 5, c = (i & 31) * 4;
    *(float4*)&qs[r * 132 + c] = *(const float4*)&q[(tn + r) * DD + c];
    *(float4*)&ks[r * 132 + c] = *(const float4*)&kref[(tm + r) * DD + c];
  }
  __syncthreads();
  float acc[4][4] = {};
  for (int k0 = 0; k0 < DD; k0 += 4) {
    float4 qv[4], kv[4];
#pragma unroll
    for (int i = 0; i < 4; ++i) qv[i] = *(const float4*)&qs[(ty * 4 + i) * 132 + k0];
#pragma unroll
    for (int j = 0; j < 4; ++j) kv[j] = *(const float4*)&ks[(tx + 16 * j) * 132 + k0];
#pragma unroll
    for (int i = 0; i < 4; ++i)
#pragma unroll
      for (int j = 0; j < 4; ++j)
        acc[i][j] = fmaf(qv[i].x, kv[j].x,
                    fmaf(qv[i].y, kv[j].y,
                    fmaf(qv[i].z, kv[j].z,
                    fmaf(qv[i].w, kv[j].w, acc[i][j]))));
  }
#pragma unroll
  for (int i = 0; i < 4; ++i)
#pragma unroll
    for (int j = 0; j < 4; ++j)
      qkout[(size_t)(tn + ty * 4 + i) * NN + tm + tx + 16 * j] = acc[i][j];
}

// ---- K3b: VT[k][m] = bf16(v[m][k])  (grid (16,4), block 256) -------------
__global__ __launch_bounds__(256) void vtrans_kernel(const float* __restrict__ v,
                                                     ushort* __restrict__ VT) {
  __shared__ float Ls[64 * 36];
  const int t = threadIdx.x;
  const int m0 = blockIdx.x * 64;
  const int kb = blockIdx.y * 32;
#pragma unroll
  for (int it = 0; it < 2; ++it) {
    const int i = t + 256 * it;          // 0..511 -> 64 rows x 8 float4
    const int m = i >> 3, c = (i & 7) * 4;
    *(float4*)&Ls[m * 36 + c] = *(const float4*)&v[(m0 + m) * DD + kb + c];
  }
  __syncthreads();
  const int k = t >> 3, mo = t & 7;
  uint32_t w[4];
#pragma unroll
  for (int p = 0; p < 4; ++p) {
    const ushort h0 = f2bf(Ls[(mo * 8 + 2 * p) * 36 + k]);
    const ushort h1 = f2bf(Ls[(mo * 8 + 2 * p + 1) * 36 + k]);
    w[p] = (uint32_t)h0 | ((uint32_t)h1 << 16);
  }
  *(uint4*)&VT[(size_t)(kb + k) * NN + m0 + mo * 8] = make_uint4(w[0], w[1], w[2], w[3]);
}

// ---- K4: fused softmax + sparse-dropout + MFMA P@V  (grid 1024, blk 256) -
__global__ __launch_bounds__(256) void attn_kernel(
    const float* __restrict__ qk, const float* __restrict__ inv_scale,
    const ushort* __restrict__ VT, float* __restrict__ out) {
  __shared__ float qkrow[NN];        // 4 KB
  __shared__ ushort VTs[128 * 132];  // 33 KB bf16 V^T tile [k][m]
  __shared__ float red[256];
  __shared__ float Sred[8 * 64];
  __shared__ float rsl[DD];

  const int n = blockIdx.x;
  const int t = threadIdx.x;
  const int l = t & 63;
  const int w = t >> 6;     // wave 0..3 -> d rows [w*32, w*32+32)
  const int g = l >> 4;     // quad
  const int li = l & 15;

  {
    const float4 v4 = *(const float4*)&qk[(size_t)n * NN + t * 4];
    *(float4*)&qkrow[t * 4] = v4;
    red[t] = fmaxf(fmaxf(v4.x, v4.y), fmaxf(v4.z, v4.w));
  }
  __syncthreads();
  for (int s = 128; s > 0; s >>= 1) {
    if (t < s) red[t] = fmaxf(red[t], red[t + s]);
    __syncthreads();
  }
  const float qkmax = red[0];

  float sd[2];
#pragma unroll
  for (int f = 0; f < 2; ++f) {
    const int d = w * 32 + f * 16 + li;
    sd[f] = 1.0f / inv_scale[n * DD + d];
  }

  float4v acc[2][8];
#pragma unroll
  for (int f = 0; f < 2; ++f)
#pragma unroll
    for (int kb = 0; kb < 8; ++kb) acc[f][kb] = (float4v)0.f;
  float sp[2] = {0.f, 0.f};

#pragma unroll 1
  for (int tile = 0; tile < 8; ++tile) {
    const int m0 = tile * 128;
    __syncthreads();
    // stage V^T tile: 128 k-rows x 128 m, bf16, row stride 132
#pragma unroll
    for (int it = 0; it < 8; ++it) {
      const int i = t + 256 * it;
      const int r = i >> 4, c = (i & 15) * 8;
      const uint4 vv = *(const uint4*)&VT[(size_t)r * NN + m0 + c];
      *(uint2*)&VTs[r * 132 + c]     = make_uint2(vv.x, vv.y);
      *(uint2*)&VTs[r * 132 + c + 4] = make_uint2(vv.z, vv.w);
    }
    __syncthreads();
#pragma unroll 1
    for (int ch = 0; ch < 4; ++ch) {
      const int ml = ch * 32 + g * 8;   // lane's m offset within tile
      const int mg = m0 + ml;           // global m of lane's first element
      float qv[8];
      {
        const float4 a = *(const float4*)&qkrow[mg];
        const float4 b = *(const float4*)&qkrow[mg + 4];
        qv[0] = a.x; qv[1] = a.y; qv[2] = a.z; qv[3] = a.w;
        qv[4] = b.x; qv[5] = b.y; qv[6] = b.z; qv[7] = b.w;
      }
      // build A fragments (P, unnormalized, dropout applied) in-register
      short8v af[2];
#pragma unroll
      for (int f = 0; f < 2; ++f) {
        const uint32_t dg = ((uint32_t)(n * DD + w * 32 + f * 16 + li)) << 10;
#pragma unroll
        for (int j = 0; j < 8; ++j) {
          const float arg = (qv[j] - qkmax) * sd[f];  // exact sub, then scale
          const float e = __expf(arg);
          sp[f] += e;
          float p = 0.f;
          if (arg > -30.f) {            // sparse: ~0.3% of elements survive
            if (keep_mask(dg + (uint32_t)(mg + j))) p = e;
          }
          af[f][j] = (short)f2bf(p);
        }
      }
      // B fragments from LDS V^T and MFMA
#pragma unroll
      for (int kb = 0; kb < 8; ++kb) {
        const ushort* rowp = &VTs[(kb * 16 + li) * 132 + ml];
        const short4v lo = *(const short4v*)rowp;
        const short4v hi = *(const short4v*)(rowp + 4);
        const short8v bf = __builtin_shufflevector(lo, hi, 0, 1, 2, 3, 4, 5, 6, 7);
        acc[0][kb] = __builtin_amdgcn_mfma_f32_16x16x32_bf16(af[0], bf, acc[0][kb], 0, 0, 0);
        acc[1][kb] = __builtin_amdgcn_mfma_f32_16x16x32_bf16(af[1], bf, acc[1][kb], 0, 0, 0);
      }
    }
  }

  // reduce S across the 4 quads sharing each d, build 1/(S*0.6)
  __syncthreads();
  Sred[(w * 2 + 0) * 64 + l] = sp[0];
  Sred[(w * 2 + 1) * 64 + l] = sp[1];
  __syncthreads();
  if (t < DD) {
    const int ww = t >> 5, ff = (t >> 4) & 1, ii = t & 15;
    const float* base = &Sred[(ww * 2 + ff) * 64];
    const float S = base[ii] + base[16 + ii] + base[32 + ii] + base[48 + ii];
    rsl[t] = 1.0f / (S * 0.6f);
  }
  __syncthreads();

  // epilogue: scale by 1/(S*0.6), write out[n][d][k]
#pragma unroll
  for (int f = 0; f < 2; ++f) {
#pragma unroll
    for (int r = 0; r < 4; ++r) {
      const int d = w * 32 + f * 16 + g * 4 + r;
      const float rs = rsl[d];
      float* op = &out[((size_t)n * DD + d) * DD + li];
#pragma unroll
      for (int kb = 0; kb < 8; ++kb)
        op[kb * 16] = acc[f][kb][r] * rs;
    }
  }
}

// ---- launch --------------------------------------------------------------
extern "C" void kernel_launch(void* const* d_in, const int* in_sizes, int n_in,
                              void* d_out, int out_size, void* d_ws, size_t ws_size,
                              hipStream_t stream) {
  const float* x1 = (const float*)d_in[0];
  const float* x2 = (const float*)d_in[1];
  const float* x3 = (const float*)d_in[2];
  const float* x4 = (const float*)d_in[3];
  const float* W  = (const float*)d_in[4];
  const float* b  = (const float*)d_in[5];
  float* out = (float*)d_out;

  float* ws  = (float*)d_ws;
  float* q   = ws;                  // 1024*128
  float* k   = ws + 131072;
  float* v   = ws + 262144;
  float* sc  = ws + 393216;
  float* inv = ws + 524288;
  float* qkm = ws + 655360;         // 1024*1024
  ushort* VT = (ushort*)(ws + 1703936);  // 128*1024 bf16

  lin_kernel<<<dim3(64, 4), 256, 0, stream>>>(x1, x2, x3, x4, W, b, q, k, v, sc);
  colsoftmax_kernel<<<DD, 256, 0, stream>>>(sc, inv);
  qk_kernel<<<dim3(16, 16), dim3(256), 0, stream>>>(q, k, qkm);
  vtrans_kernel<<<dim3(16, 4), 256, 0, stream>>>(v, VT);
  attn_kernel<<<NN, 256, 0, stream>>>(qkm, inv, VT, out);
}

// Round 3
// 197.952 us; speedup vs baseline: 5.5561x; 1.0560x over previous
//
#include <hip/hip_runtime.h>
#include <stdint.h>
#include <math.h>

static constexpr int NN  = 1024;   // N
static constexpr int DIN = 512;    // D_IN
static constexpr int DD  = 128;    // D_OUT

// ---- threefry2x32, key = jax.random.key(42) => (0,42), partitionable ----
__device__ __forceinline__ uint32_t rotl32(uint32_t x, uint32_t r) {
  return (x << r) | (x >> (32u - r));
}

__device__ __forceinline__ bool keep_mask(uint32_t idx) {
  uint32_t x0 = 0u, x1 = idx;
  const uint32_t k0 = 0u, k1 = 42u;
  const uint32_t k2 = k0 ^ k1 ^ 0x1BD11BDAu;
  x0 += k0; x1 += k1;
#define TF_ROUND(r) { x0 += x1; x1 = rotl32(x1, r); x1 ^= x0; }
  TF_ROUND(13u) TF_ROUND(15u) TF_ROUND(26u) TF_ROUND(6u)
  x0 += k1; x1 += k2 + 1u;
  TF_ROUND(17u) TF_ROUND(29u) TF_ROUND(16u) TF_ROUND(24u)
  x0 += k2; x1 += k0 + 2u;
  TF_ROUND(13u) TF_ROUND(15u) TF_ROUND(26u) TF_ROUND(6u)
  x0 += k0; x1 += k1 + 3u;
  TF_ROUND(17u) TF_ROUND(29u) TF_ROUND(16u) TF_ROUND(24u)
  x0 += k1; x1 += k2 + 4u;
  TF_ROUND(13u) TF_ROUND(15u) TF_ROUND(26u) TF_ROUND(6u)
  x0 += k2; x1 += k0 + 5u;
#undef TF_ROUND
  const uint32_t bits = x0 ^ x1;
  const float u = __uint_as_float((bits >> 9) | 0x3f800000u) - 1.0f;
  return u < 0.6f;
}

// ---- K1: q,k,v,scale = x_i @ W.T + b  (unchanged from round 2) -----------
__global__ __launch_bounds__(256) void lin_kernel(
    const float* __restrict__ x1, const float* __restrict__ x2,
    const float* __restrict__ x3, const float* __restrict__ x4,
    const float* __restrict__ W, const float* __restrict__ bias,
    float* __restrict__ q, float* __restrict__ kk,
    float* __restrict__ v, float* __restrict__ sc) {
  __shared__ float Ws[128 * 66];
  __shared__ float Xs[16 * 68];
  const int t = threadIdx.x;
  const int n0 = blockIdx.x * 16;
  const int mat = blockIdx.y;
  const float* x = (mat == 0) ? x1 : (mat == 1) ? x2 : (mat == 2) ? x3 : x4;
  float* o = (mat == 0) ? q : (mat == 1) ? kk : (mat == 2) ? v : sc;
  const int tx = t & 31;
  const int ty = t >> 5;
  float acc[2][4] = {{0.f, 0.f, 0.f, 0.f}, {0.f, 0.f, 0.f, 0.f}};
  for (int kt = 0; kt < 8; ++kt) {
    const int k0 = kt * 64;
    __syncthreads();
    for (int it = 0; it < 8; ++it) {
      const int i = t + 256 * it;
      const int r = i >> 4, c = (i & 15) * 4;
      const float4 wv = *(const float4*)&W[r * DIN + k0 + c];
      *(float2*)&Ws[r * 66 + c]     = make_float2(wv.x, wv.y);
      *(float2*)&Ws[r * 66 + c + 2] = make_float2(wv.z, wv.w);
    }
    {
      const int r = t >> 4, c = (t & 15) * 4;
      *(float4*)&Xs[r * 68 + c] = *(const float4*)&x[(n0 + r) * DIN + k0 + c];
    }
    __syncthreads();
    for (int c4 = 0; c4 < 64; c4 += 4) {
      const float4 xa = *(const float4*)&Xs[(ty * 2 + 0) * 68 + c4];
      const float4 xb = *(const float4*)&Xs[(ty * 2 + 1) * 68 + c4];
#pragma unroll
      for (int j = 0; j < 4; ++j) {
        const float2 w0 = *(const float2*)&Ws[(tx + 32 * j) * 66 + c4];
        const float2 w1 = *(const float2*)&Ws[(tx + 32 * j) * 66 + c4 + 2];
        acc[0][j] = fmaf(xa.x, w0.x, fmaf(xa.y, w0.y, fmaf(xa.z, w1.x, fmaf(xa.w, w1.y, acc[0][j]))));
        acc[1][j] = fmaf(xb.x, w0.x, fmaf(xb.y, w0.y, fmaf(xb.z, w1.x, fmaf(xb.w, w1.y, acc[1][j]))));
      }
    }
  }
#pragma unroll
  for (int r = 0; r < 2; ++r)
#pragma unroll
    for (int j = 0; j < 4; ++j) {
      const int d = tx + 32 * j;
      o[(n0 + ty * 2 + r) * DD + d] = acc[r][j] + bias[d];
    }
}

// ---- K2: inv_scale = softmax(scale, axis=0)  (grid 128, block 256) -------
__global__ void colsoftmax_kernel(const float* __restrict__ sc,
                                  float* __restrict__ inv) {
  __shared__ float red[256];
  const int d = blockIdx.x;
  const int t = threadIdx.x;
  float vals[4];
  float mx = -INFINITY;
#pragma unroll
  for (int i = 0; i < 4; ++i) {
    vals[i] = sc[(size_t)(t + 256 * i) * DD + d];
    mx = fmaxf(mx, vals[i]);
  }
  red[t] = mx; __syncthreads();
  for (int s = 128; s > 0; s >>= 1) {
    if (t < s) red[t] = fmaxf(red[t], red[t + s]);
    __syncthreads();
  }
  mx = red[0]; __syncthreads();
  float e[4]; float sm = 0.f;
#pragma unroll
  for (int i = 0; i < 4; ++i) { e[i] = expf(vals[i] - mx); sm += e[i]; }
  red[t] = sm; __syncthreads();
  for (int s = 128; s > 0; s >>= 1) {
    if (t < s) red[t] += red[t + s];
    __syncthreads();
  }
  sm = red[0];
#pragma unroll
  for (int i = 0; i < 4; ++i)
    inv[(size_t)(t + 256 * i) * DD + d] = e[i] / sm;
}

// ---- K3: qk = q @ k.T  (unchanged from round 2) --------------------------
__global__ __launch_bounds__(256) void qk_kernel(
    const float* __restrict__ q, const float* __restrict__ kref,
    float* __restrict__ qkout) {
  __shared__ float qs[64 * 132];
  __shared__ float ks[64 * 132];
  const int t = threadIdx.x;
  const int tx = t & 15, ty = t >> 4;
  const int tm = blockIdx.x * 64, tn = blockIdx.y * 64;
  for (int it = 0; it < 8; ++it) {
    const int i = t + 256 * it;
    const int r = i >> 5, c = (i & 31) * 4;
    *(float4*)&qs[r * 132 + c] = *(const float4*)&q[(tn + r) * DD + c];
    *(float4*)&ks[r * 132 + c] = *(const float4*)&kref[(tm + r) * DD + c];
  }
  __syncthreads();
  float acc[4][4] = {};
  for (int k0 = 0; k0 < DD; k0 += 4) {
    float4 qv[4], kv[4];
#pragma unroll
    for (int i = 0; i < 4; ++i) qv[i] = *(const float4*)&qs[(ty * 4 + i) * 132 + k0];
#pragma unroll
    for (int j = 0; j < 4; ++j) kv[j] = *(const float4*)&ks[(tx + 16 * j) * 132 + k0];
#pragma unroll
    for (int i = 0; i < 4; ++i)
#pragma unroll
      for (int j = 0; j < 4; ++j)
        acc[i][j] = fmaf(qv[i].x, kv[j].x,
                    fmaf(qv[i].y, kv[j].y,
                    fmaf(qv[i].z, kv[j].z,
                    fmaf(qv[i].w, kv[j].w, acc[i][j]))));
  }
#pragma unroll
  for (int i = 0; i < 4; ++i)
#pragma unroll
    for (int j = 0; j < 4; ++j)
      qkout[(size_t)(tn + ty * 4 + i) * NN + tm + tx + 16 * j] = acc[i][j];
}

// ---- K4: sparse softmax-dropout-PV  (grid 1024, block 256) ---------------
// Key fact: sd = 1/inv_scale >= ~66 amplifies logits so the softmax is a
// near-argmax. Survivor gate (union over d): qv > qkmax - 30*max_d(inv).
// Non-survivors have arg < -30 for EVERY d -> e < 9.4e-14; round 2 already
// zeroed P below e^-30 and passed; dropping them from S costs < 1e-10 rel.
__global__ __launch_bounds__(256) void attn_kernel(
    const float* __restrict__ qk, const float* __restrict__ inv_scale,
    const float* __restrict__ v, float* __restrict__ out) {
  __shared__ float qkrow[NN];      // 4 KB
  __shared__ float red[8];
  __shared__ int   surv[NN];       // 4 KB (worst case fully dense -> correct)
  __shared__ float Pl[16][130];    // 8.3 KB  P chunk [s][d]
  __shared__ float Vs[16][132];    // 8.4 KB  V chunk [s][k]
  __shared__ float sdv[DD];
  __shared__ float Sfin[DD];
  __shared__ int   cnt;

  const int n = blockIdx.x;
  const int t = threadIdx.x;

  // load qk row (float4/lane), wave-reduce max, cross-wave via LDS
  const float4 q4 = *(const float4*)&qk[(size_t)n * NN + t * 4];
  *(float4*)&qkrow[t * 4] = q4;
  float mx = fmaxf(fmaxf(q4.x, q4.y), fmaxf(q4.z, q4.w));
#pragma unroll
  for (int o = 32; o > 0; o >>= 1) mx = fmaxf(mx, __shfl_xor(mx, o));
  if ((t & 63) == 0) red[t >> 6] = mx;
  // inv row + its max
  float iv = 0.f;
  if (t < DD) { iv = inv_scale[n * DD + t]; sdv[t] = 1.0f / iv; }
  float miv = iv;
#pragma unroll
  for (int o = 32; o > 0; o >>= 1) miv = fmaxf(miv, __shfl_xor(miv, o));
  if ((t & 63) == 0) red[4 + (t >> 6)] = miv;
  if (t == 0) cnt = 0;
  __syncthreads();
  const float qkmax = fmaxf(fmaxf(red[0], red[1]), fmaxf(red[2], red[3]));
  const float maxinv = fmaxf(red[4], red[5]);  // waves 2,3 wrote 0
  const float th = qkmax - 30.f * maxinv;

  // survivor gather (typically 1-3 of 1024)
  {
    const float qv[4] = {q4.x, q4.y, q4.z, q4.w};
#pragma unroll
    for (int j = 0; j < 4; ++j)
      if (qv[j] > th) { const int p = atomicAdd(&cnt, 1); surv[p] = t * 4 + j; }
  }
  __syncthreads();
  const int K = cnt;

  const int dt = t >> 1;         // output d owned by this thread
  const int kh = t & 1;          // which 64-wide k half
  float4 acc4[16];
#pragma unroll
  for (int i = 0; i < 16; ++i) acc4[i] = make_float4(0.f, 0.f, 0.f, 0.f);
  float Sloc = 0.f;              // valid for t < 128 (d = t)

  for (int c0 = 0; c0 < K; c0 += 16) {
    const int C = min(16, K - c0);
    __syncthreads();             // protect Pl/Vs from previous chunk readers
    if (t < DD) {
      // P-build: thread t owns d=t; ~C exps
      const float sd = sdv[t];
      const uint32_t dg = ((uint32_t)(n * DD + t)) << 10;
      for (int s = 0; s < C; ++s) {
        const int m = surv[c0 + s];
        const float arg = (qkrow[m] - qkmax) * sd;
        const float e = __expf(arg);
        Sloc += e;
        float p = 0.f;
        if (arg > -30.f) {
          if (keep_mask(dg + (uint32_t)m)) p = e;
        }
        Pl[s][t] = p;
      }
    } else {
      // V-stage: threads 128..255 load the chunk's V rows (fp32, coalesced)
      const int u = t - 128;
      for (int slot = u; slot < C * 32; slot += 128) {
        const int s = slot >> 5, c = (slot & 31) * 4;
        *(float4*)&Vs[s][c] = *(const float4*)&v[(size_t)surv[c0 + s] * DD + c];
      }
    }
    __syncthreads();
    // rank-C accumulate: out[dt, kh*64 .. +64) += p * V[s, :]
    for (int s = 0; s < C; ++s) {
      const float p = Pl[s][dt];
      const float* vr = &Vs[s][kh * 64];
#pragma unroll
      for (int i = 0; i < 16; ++i) {
        const float4 vv = *(const float4*)&vr[i * 4];
        acc4[i].x = fmaf(p, vv.x, acc4[i].x);
        acc4[i].y = fmaf(p, vv.y, acc4[i].y);
        acc4[i].z = fmaf(p, vv.z, acc4[i].z);
        acc4[i].w = fmaf(p, vv.w, acc4[i].w);
      }
    }
  }

  __syncthreads();
  if (t < DD) Sfin[t] = Sloc;
  __syncthreads();
  const float rs = 1.0f / (Sfin[dt] * 0.6f);
  float* op = &out[((size_t)n * DD + dt) * DD + kh * 64];
#pragma unroll
  for (int i = 0; i < 16; ++i) {
    float4 r = acc4[i];
    r.x *= rs; r.y *= rs; r.z *= rs; r.w *= rs;
    *(float4*)&op[i * 4] = r;
  }
}

// ---- launch --------------------------------------------------------------
extern "C" void kernel_launch(void* const* d_in, const int* in_sizes, int n_in,
                              void* d_out, int out_size, void* d_ws, size_t ws_size,
                              hipStream_t stream) {
  const float* x1 = (const float*)d_in[0];
  const float* x2 = (const float*)d_in[1];
  const float* x3 = (const float*)d_in[2];
  const float* x4 = (const float*)d_in[3];
  const float* W  = (const float*)d_in[4];
  const float* b  = (const float*)d_in[5];
  float* out = (float*)d_out;

  float* ws  = (float*)d_ws;
  float* q   = ws;                  // 1024*128
  float* k   = ws + 131072;
  float* v   = ws + 262144;
  float* sc  = ws + 393216;
  float* inv = ws + 524288;
  float* qkm = ws + 655360;         // 1024*1024

  lin_kernel<<<dim3(64, 4), 256, 0, stream>>>(x1, x2, x3, x4, W, b, q, k, v, sc);
  colsoftmax_kernel<<<DD, 256, 0, stream>>>(sc, inv);
  qk_kernel<<<dim3(16, 16), dim3(256), 0, stream>>>(q, k, qkm);
  attn_kernel<<<NN, 256, 0, stream>>>(qkm, inv, v, out);
}

// Round 4
// 126.663 us; speedup vs baseline: 8.6832x; 1.5628x over previous
//
#include <hip/hip_runtime.h>
#include <stdint.h>
#include <math.h>

static constexpr int NN  = 1024;   // N
static constexpr int DIN = 512;    // D_IN
static constexpr int DD  = 128;    // D_OUT

// ---- threefry2x32, key = jax.random.key(42) => (0,42), partitionable ----
__device__ __forceinline__ uint32_t rotl32(uint32_t x, uint32_t r) {
  return (x << r) | (x >> (32u - r));
}

__device__ __forceinline__ bool keep_mask(uint32_t idx) {
  uint32_t x0 = 0u, x1 = idx;
  const uint32_t k0 = 0u, k1 = 42u;
  const uint32_t k2 = k0 ^ k1 ^ 0x1BD11BDAu;
  x0 += k0; x1 += k1;
#define TF_ROUND(r) { x0 += x1; x1 = rotl32(x1, r); x1 ^= x0; }
  TF_ROUND(13u) TF_ROUND(15u) TF_ROUND(26u) TF_ROUND(6u)
  x0 += k1; x1 += k2 + 1u;
  TF_ROUND(17u) TF_ROUND(29u) TF_ROUND(16u) TF_ROUND(24u)
  x0 += k2; x1 += k0 + 2u;
  TF_ROUND(13u) TF_ROUND(15u) TF_ROUND(26u) TF_ROUND(6u)
  x0 += k0; x1 += k1 + 3u;
  TF_ROUND(17u) TF_ROUND(29u) TF_ROUND(16u) TF_ROUND(24u)
  x0 += k1; x1 += k2 + 4u;
  TF_ROUND(13u) TF_ROUND(15u) TF_ROUND(26u) TF_ROUND(6u)
  x0 += k2; x1 += k0 + 5u;
#undef TF_ROUND
  const uint32_t bits = x0 ^ x1;
  const float u = __uint_as_float((bits >> 9) | 0x3f800000u) - 1.0f;
  return u < 0.6f;
}

// ---- K1: q,k,v,scale = x_i @ W.T + b  (grid (128,4), block 256) ----------
// 8 n-rows x 128 d per block -> 512 blocks (2/CU) for latency hiding.
__global__ __launch_bounds__(256) void lin_kernel(
    const float* __restrict__ x1, const float* __restrict__ x2,
    const float* __restrict__ x3, const float* __restrict__ x4,
    const float* __restrict__ W, const float* __restrict__ bias,
    float* __restrict__ q, float* __restrict__ kk,
    float* __restrict__ v, float* __restrict__ sc) {
  __shared__ float Ws[128 * 66];
  __shared__ float Xs[8 * 68];
  const int t = threadIdx.x;
  const int n0 = blockIdx.x * 8;
  const int mat = blockIdx.y;
  const float* x = (mat == 0) ? x1 : (mat == 1) ? x2 : (mat == 2) ? x3 : x4;
  float* o = (mat == 0) ? q : (mat == 1) ? kk : (mat == 2) ? v : sc;
  const int tx = t & 31;   // d-lane: owns d = tx + 32j
  const int ty = t >> 5;   // row: n = n0 + ty
  float acc[4] = {0.f, 0.f, 0.f, 0.f};
  for (int kt = 0; kt < 8; ++kt) {
    const int k0 = kt * 64;
    __syncthreads();
    // stage W tile 128x64
    for (int it = 0; it < 8; ++it) {
      const int i = t + 256 * it;
      const int r = i >> 4, c = (i & 15) * 4;
      const float4 wv = *(const float4*)&W[r * DIN + k0 + c];
      *(float2*)&Ws[r * 66 + c]     = make_float2(wv.x, wv.y);
      *(float2*)&Ws[r * 66 + c + 2] = make_float2(wv.z, wv.w);
    }
    // stage X tile 8x64
    if (t < 128) {
      const int r = t >> 4, c = (t & 15) * 4;
      *(float4*)&Xs[r * 68 + c] = *(const float4*)&x[(n0 + r) * DIN + k0 + c];
    }
    __syncthreads();
    for (int c4 = 0; c4 < 64; c4 += 4) {
      const float4 xa = *(const float4*)&Xs[ty * 68 + c4];
#pragma unroll
      for (int j = 0; j < 4; ++j) {
        const float2 w0 = *(const float2*)&Ws[(tx + 32 * j) * 66 + c4];
        const float2 w1 = *(const float2*)&Ws[(tx + 32 * j) * 66 + c4 + 2];
        acc[j] = fmaf(xa.x, w0.x, fmaf(xa.y, w0.y, fmaf(xa.z, w1.x, fmaf(xa.w, w1.y, acc[j]))));
      }
    }
  }
#pragma unroll
  for (int j = 0; j < 4; ++j) {
    const int d = tx + 32 * j;
    o[(n0 + ty) * DD + d] = acc[j] + bias[d];
  }
}

// ---- K2: fused qk = q@k.T (blocks 0..255) + colsoftmax (blocks 256..383) -
__global__ __launch_bounds__(256) void mid_kernel(
    const float* __restrict__ q, const float* __restrict__ kref,
    const float* __restrict__ sc, float* __restrict__ qkout,
    float* __restrict__ inv) {
  const int t = threadIdx.x;
  if (blockIdx.x < 256) {
    // ---- qk: 64x64 tile, 4x4 per thread ----
    __shared__ float qs[64 * 132];
    __shared__ float ks[64 * 132];
    const int tx = t & 15, ty = t >> 4;
    const int tm = (blockIdx.x & 15) * 64, tn = (blockIdx.x >> 4) * 64;
    for (int it = 0; it < 8; ++it) {
      const int i = t + 256 * it;
      const int r = i >> 5, c = (i & 31) * 4;
      *(float4*)&qs[r * 132 + c] = *(const float4*)&q[(tn + r) * DD + c];
      *(float4*)&ks[r * 132 + c] = *(const float4*)&kref[(tm + r) * DD + c];
    }
    __syncthreads();
    float acc[4][4] = {};
    for (int k0 = 0; k0 < DD; k0 += 4) {
      float4 qv[4], kv[4];
#pragma unroll
      for (int i = 0; i < 4; ++i) qv[i] = *(const float4*)&qs[(ty * 4 + i) * 132 + k0];
#pragma unroll
      for (int j = 0; j < 4; ++j) kv[j] = *(const float4*)&ks[(tx + 16 * j) * 132 + k0];
#pragma unroll
      for (int i = 0; i < 4; ++i)
#pragma unroll
        for (int j = 0; j < 4; ++j)
          acc[i][j] = fmaf(qv[i].x, kv[j].x,
                      fmaf(qv[i].y, kv[j].y,
                      fmaf(qv[i].z, kv[j].z,
                      fmaf(qv[i].w, kv[j].w, acc[i][j]))));
    }
#pragma unroll
    for (int i = 0; i < 4; ++i)
#pragma unroll
      for (int j = 0; j < 4; ++j)
        qkout[(size_t)(tn + ty * 4 + i) * NN + tm + tx + 16 * j] = acc[i][j];
  } else {
    // ---- column softmax over n for d = blockIdx.x - 256 ----
    __shared__ float red[256];
    const int d = blockIdx.x - 256;
    float vals[4];
    float mx = -INFINITY;
#pragma unroll
    for (int i = 0; i < 4; ++i) {
      vals[i] = sc[(size_t)(t + 256 * i) * DD + d];
      mx = fmaxf(mx, vals[i]);
    }
    red[t] = mx; __syncthreads();
    for (int s = 128; s > 0; s >>= 1) {
      if (t < s) red[t] = fmaxf(red[t], red[t + s]);
      __syncthreads();
    }
    mx = red[0]; __syncthreads();
    float e[4]; float sm = 0.f;
#pragma unroll
    for (int i = 0; i < 4; ++i) { e[i] = expf(vals[i] - mx); sm += e[i]; }
    red[t] = sm; __syncthreads();
    for (int s = 128; s > 0; s >>= 1) {
      if (t < s) red[t] += red[t + s];
      __syncthreads();
    }
    sm = red[0];
#pragma unroll
    for (int i = 0; i < 4; ++i)
      inv[(size_t)(t + 256 * i) * DD + d] = e[i] / sm;
  }
}

// ---- K3: sparse softmax-dropout-PV  (grid 1024, block 256) ---------------
// Survivor gate: qv > qkmax - 30*max_d(inv) => ~1-3 survivors of 1024.
// New ownership for COALESCED output: thread t owns k4=(t&31)*4 and
// d in {g*8 + (t>>5)}, so store g covers out[n*16384 + g*1024 + t*4]
// -> 1 KB contiguous per wave-store, no partial-cacheline eviction.
__global__ __launch_bounds__(256) void attn_kernel(
    const float* __restrict__ qk, const float* __restrict__ inv_scale,
    const float* __restrict__ v, float* __restrict__ out) {
  __shared__ float qkrow[NN];      // 4 KB
  __shared__ float red[8];
  __shared__ int   surv[NN];       // 4 KB (worst case dense -> still correct)
  __shared__ float Pl[16][130];    // P chunk [s][d]
  __shared__ float Vs[16][132];    // V chunk [s][k]
  __shared__ float sdv[DD];
  __shared__ float rsl[DD];
  __shared__ int   cnt;

  const int n = blockIdx.x;
  const int t = threadIdx.x;

  const float4 q4 = *(const float4*)&qk[(size_t)n * NN + t * 4];
  *(float4*)&qkrow[t * 4] = q4;
  float mx = fmaxf(fmaxf(q4.x, q4.y), fmaxf(q4.z, q4.w));
#pragma unroll
  for (int o = 32; o > 0; o >>= 1) mx = fmaxf(mx, __shfl_xor(mx, o));
  if ((t & 63) == 0) red[t >> 6] = mx;
  float iv = 0.f;
  if (t < DD) { iv = inv_scale[n * DD + t]; sdv[t] = 1.0f / iv; }
  float miv = iv;
#pragma unroll
  for (int o = 32; o > 0; o >>= 1) miv = fmaxf(miv, __shfl_xor(miv, o));
  if ((t & 63) == 0) red[4 + (t >> 6)] = miv;
  if (t == 0) cnt = 0;
  __syncthreads();
  const float qkmax = fmaxf(fmaxf(red[0], red[1]), fmaxf(red[2], red[3]));
  const float maxinv = fmaxf(red[4], red[5]);
  const float th = qkmax - 30.f * maxinv;

  {
    const float qv[4] = {q4.x, q4.y, q4.z, q4.w};
#pragma unroll
    for (int j = 0; j < 4; ++j)
      if (qv[j] > th) { const int p = atomicAdd(&cnt, 1); surv[p] = t * 4 + j; }
  }
  __syncthreads();
  const int K = cnt;

  const int k4 = (t & 31) * 4;
  const int dbase = t >> 5;       // 0..7
  float4 acc4[16];
#pragma unroll
  for (int g = 0; g < 16; ++g) acc4[g] = make_float4(0.f, 0.f, 0.f, 0.f);
  float Sloc = 0.f;               // valid for t < 128 (d = t)

  for (int c0 = 0; c0 < K; c0 += 16) {
    const int C = min(16, K - c0);
    __syncthreads();
    if (t < DD) {
      const float sd = sdv[t];
      const uint32_t dg = ((uint32_t)(n * DD + t)) << 10;
      for (int s = 0; s < C; ++s) {
        const int m = surv[c0 + s];
        const float arg = (qkrow[m] - qkmax) * sd;
        const float e = __expf(arg);
        Sloc += e;
        float p = 0.f;
        if (arg > -30.f) {
          if (keep_mask(dg + (uint32_t)m)) p = e;
        }
        Pl[s][t] = p;
      }
    } else {
      const int u = t - 128;
      for (int slot = u; slot < C * 32; slot += 128) {
        const int s = slot >> 5, c = (slot & 31) * 4;
        *(float4*)&Vs[s][c] = *(const float4*)&v[(size_t)surv[c0 + s] * DD + c];
      }
    }
    __syncthreads();
    for (int s = 0; s < C; ++s) {
      const float4 vv = *(const float4*)&Vs[s][k4];
#pragma unroll
      for (int g = 0; g < 16; ++g) {
        const float p = Pl[s][g * 8 + dbase];
        acc4[g].x = fmaf(p, vv.x, acc4[g].x);
        acc4[g].y = fmaf(p, vv.y, acc4[g].y);
        acc4[g].z = fmaf(p, vv.z, acc4[g].z);
        acc4[g].w = fmaf(p, vv.w, acc4[g].w);
      }
    }
  }

  __syncthreads();
  if (t < DD) rsl[t] = 1.0f / (Sloc * 0.6f);
  __syncthreads();
  float* op = &out[(size_t)n * (DD * DD) + t * 4];
#pragma unroll
  for (int g = 0; g < 16; ++g) {
    const float rs = rsl[g * 8 + dbase];
    float4 r = acc4[g];
    r.x *= rs; r.y *= rs; r.z *= rs; r.w *= rs;
    *(float4*)&op[g * 1024] = r;
  }
}

// ---- launch --------------------------------------------------------------
extern "C" void kernel_launch(void* const* d_in, const int* in_sizes, int n_in,
                              void* d_out, int out_size, void* d_ws, size_t ws_size,
                              hipStream_t stream) {
  const float* x1 = (const float*)d_in[0];
  const float* x2 = (const float*)d_in[1];
  const float* x3 = (const float*)d_in[2];
  const float* x4 = (const float*)d_in[3];
  const float* W  = (const float*)d_in[4];
  const float* b  = (const float*)d_in[5];
  float* out = (float*)d_out;

  float* ws  = (float*)d_ws;
  float* q   = ws;                  // 1024*128
  float* k   = ws + 131072;
  float* v   = ws + 262144;
  float* sc  = ws + 393216;
  float* inv = ws + 524288;
  float* qkm = ws + 655360;         // 1024*1024

  lin_kernel<<<dim3(128, 4), 256, 0, stream>>>(x1, x2, x3, x4, W, b, q, k, v, sc);
  mid_kernel<<<dim3(384), 256, 0, stream>>>(q, k, sc, qkm, inv);
  attn_kernel<<<NN, 256, 0, stream>>>(qkm, inv, v, out);
}